// Round 1
// baseline (2262.698 us; speedup 1.0000x reference)
//
#include <hip/hip_runtime.h>
#include <hip/hip_bf16.h>
#include <math.h>

#define HH 128
#define WW 128
#define HWSZ 16384
#define BB 2
#define NPIX 32768   // BB*HWSZ

// ---------------- generic 3x3 conv, pad=1, input = concat(in0[0:csplit], in1[csplit:Cin]) ----
__global__ __launch_bounds__(256) void conv3x3_kernel(
    const float* __restrict__ in0, const float* __restrict__ in1, int csplit, int Cin,
    const float* __restrict__ wgt, const float* __restrict__ bias,
    float* __restrict__ out, int Cout)
{
    const int ocb = Cout >> 3;
    const int oc8 = blockIdx.z % ocb;
    const int b   = blockIdx.z / ocb;
    const int h0 = blockIdx.y * 16, w0 = blockIdx.x * 16;
    const int tid = threadIdx.x;
    const int tx = tid & 15, ty = tid >> 4;

    __shared__ float s_in[8][18 * 18];
    __shared__ float s_w[8][8][9];

    float acc[8];
#pragma unroll
    for (int oc = 0; oc < 8; ++oc) acc[oc] = bias[oc8 * 8 + oc];

    for (int cb = 0; cb < Cin; cb += 8) {
        __syncthreads();
        for (int i = tid; i < 8 * 324; i += 256) {
            int ic = i / 324, r = i % 324;
            int yy = r / 18, xx = r % 18;
            int gy = h0 + yy - 1, gx = w0 + xx - 1;
            float v = 0.f;
            if ((unsigned)gy < HH && (unsigned)gx < WW) {
                int c = cb + ic;
                const float* src; int cc, cpart;
                if (c < csplit) { src = in0; cc = c; cpart = csplit; }
                else            { src = in1; cc = c - csplit; cpart = Cin - csplit; }
                v = src[(((size_t)b * cpart + cc) * HH + gy) * WW + gx];
            }
            s_in[ic][r] = v;
        }
        for (int i = tid; i < 8 * 8 * 9; i += 256) {
            int oc = i / 72, r = i % 72;
            int ic = r / 9, k = r % 9;
            s_w[oc][ic][k] = wgt[(((size_t)(oc8 * 8 + oc)) * Cin + cb + ic) * 9 + k];
        }
        __syncthreads();
#pragma unroll
        for (int ic = 0; ic < 8; ++ic) {
            float v[9];
#pragma unroll
            for (int ky = 0; ky < 3; ++ky)
#pragma unroll
                for (int kx = 0; kx < 3; ++kx)
                    v[ky * 3 + kx] = s_in[ic][(ty + ky) * 18 + tx + kx];
#pragma unroll
            for (int oc = 0; oc < 8; ++oc) {
                float a = acc[oc];
#pragma unroll
                for (int k = 0; k < 9; ++k) a = fmaf(v[k], s_w[oc][ic][k], a);
                acc[oc] = a;
            }
        }
    }
    const int h = h0 + ty, w = w0 + tx;
#pragma unroll
    for (int oc = 0; oc < 8; ++oc)
        out[(((size_t)b * Cout + oc8 * 8 + oc) * HH + h) * WW + w] = acc[oc];
}

// ---------------- l2norm (optional) + transpose to (B,H,W,C) ----------------
__global__ __launch_bounds__(256) void l2t_kernel(const float* __restrict__ in,
                                                  float* __restrict__ outT, int do_norm)
{
    const int pix0 = blockIdx.x * 64;
    const int b = pix0 >> 14;
    const int hw0 = pix0 & (HWSZ - 1);
    __shared__ float s[64][65];
    __shared__ float sinv[64];
    const int tid = threadIdx.x;
    {
        const int p = tid & 63, c4 = tid >> 6;
#pragma unroll
        for (int r = 0; r < 16; ++r) {
            int c = r * 4 + c4;
            s[c][p] = in[(((size_t)b * 64 + c) << 14) + hw0 + p];
        }
    }
    __syncthreads();
    if (tid < 64) {
        float sum = 0.f;
#pragma unroll
        for (int c = 0; c < 64; ++c) { float v = s[c][tid]; sum = fmaf(v, v, sum); }
        sinv[tid] = do_norm ? (1.f / fmaxf(sqrtf(sum), 1e-12f)) : 1.f;
    }
    __syncthreads();
    {
        const int c = tid & 63, p4 = tid >> 6;
#pragma unroll
        for (int r = 0; r < 16; ++r) {
            int pp = r * 4 + p4;
            outT[((size_t)(pix0 + pp)) * 64 + c] = s[c][pp] * sinv[pp];
        }
    }
}

// ---------------- per-displacement dot products D[b][p][hw] ----------------
__global__ __launch_bounds__(256) void dot_kernel(const float* __restrict__ f1t,
                                                  const float* __restrict__ f2t,
                                                  float* __restrict__ D)
{
    const int pix = blockIdx.x * 256 + threadIdx.x;
    const int q = blockIdx.y;
    const int b = pix >> 14, hw = pix & (HWSZ - 1), h = hw >> 7, w = hw & 127;
    float4 f1[16];
    const float4* f1p = (const float4*)(f1t + (size_t)pix * 64);
#pragma unroll
    for (int i = 0; i < 16; ++i) f1[i] = f1p[i];
    const size_t dbase = ((size_t)b * 121) << 14;
    for (int p = q; p < 121; p += 4) {
        int dy = p / 11 - 5, dx = p % 11 - 5;
        int y = h + dy, x = w + dx;
        float s = 0.f;
        if ((unsigned)y < HH && (unsigned)x < WW) {
            const float4* f2p = (const float4*)(f2t + ((((size_t)b << 14) | (y << 7) | x)) * 64);
#pragma unroll
            for (int i = 0; i < 16; ++i) {
                float4 a = f1[i], c = f2p[i];
                s += a.x * c.x + a.y * c.y + a.z * c.z + a.w * c.w;
            }
        }
        D[dbase + ((size_t)p << 14) + hw] = s;
    }
}

// ---------------- 3x3 box-sum of D + stable top-4 over 121 ----------------
__global__ __launch_bounds__(256) void topk_kernel(const float* __restrict__ D,
                                                   int* __restrict__ idxout)
{
    const int tid = threadIdx.x;
    const int lp = tid & 63, tq = tid >> 6;   // 64 pixels/block, 4 threads/pixel
    const int pix = blockIdx.x * 64 + lp;
    const int b = pix >> 14, hw = pix & (HWSZ - 1), h = hw >> 7, w = hw & 127;
    const size_t dbase = ((size_t)b * 121) << 14;

    float bv[4] = {-1e30f, -1e30f, -1e30f, -1e30f};
    int   bi[4] = {1000, 1000, 1000, 1000};
    for (int p = tq; p < 121; p += 4) {      // ascending p within thread -> stable
        float s = 0.f;
#pragma unroll
        for (int dy = -1; dy <= 1; ++dy) {
            int y = h + dy; if ((unsigned)y >= HH) continue;
#pragma unroll
            for (int dx = -1; dx <= 1; ++dx) {
                int x = w + dx; if ((unsigned)x >= WW) continue;
                s += D[dbase + ((size_t)p << 14) + (y << 7) + x];
            }
        }
        if (s > bv[3]) {
            if (s > bv[0]) { bv[3]=bv[2];bi[3]=bi[2]; bv[2]=bv[1];bi[2]=bi[1]; bv[1]=bv[0];bi[1]=bi[0]; bv[0]=s; bi[0]=p; }
            else if (s > bv[1]) { bv[3]=bv[2];bi[3]=bi[2]; bv[2]=bv[1];bi[2]=bi[1]; bv[1]=s; bi[1]=p; }
            else if (s > bv[2]) { bv[3]=bv[2];bi[3]=bi[2]; bv[2]=s; bi[2]=p; }
            else { bv[3]=s; bi[3]=p; }
        }
    }
    __shared__ float sv[4][64][4];
    __shared__ int   si[4][64][4];
#pragma unroll
    for (int r = 0; r < 4; ++r) { sv[tq][lp][r] = bv[r]; si[tq][lp][r] = bi[r]; }
    __syncthreads();
    if (tq == 0) {
        float bv2[4] = {-1e30f, -1e30f, -1e30f, -1e30f};
        int   bi2[4] = {100000, 100000, 100000, 100000};
#pragma unroll
        for (int t = 0; t < 4; ++t)
#pragma unroll
            for (int r = 0; r < 4; ++r) {
                float v = sv[t][lp][r]; int pp = si[t][lp][r];
                // rank: better iff v>V or (v==V and p<P)  -> order-independent stable merge
                bool g3 = (v > bv2[3]) || (v == bv2[3] && pp < bi2[3]);
                if (g3) {
                    bool g0 = (v > bv2[0]) || (v == bv2[0] && pp < bi2[0]);
                    bool g1 = (v > bv2[1]) || (v == bv2[1] && pp < bi2[1]);
                    bool g2 = (v > bv2[2]) || (v == bv2[2] && pp < bi2[2]);
                    if (g0) { bv2[3]=bv2[2];bi2[3]=bi2[2]; bv2[2]=bv2[1];bi2[2]=bi2[1]; bv2[1]=bv2[0];bi2[1]=bi2[0]; bv2[0]=v; bi2[0]=pp; }
                    else if (g1) { bv2[3]=bv2[2];bi2[3]=bi2[2]; bv2[2]=bv2[1];bi2[2]=bi2[1]; bv2[1]=v; bi2[1]=pp; }
                    else if (g2) { bv2[3]=bv2[2];bi2[3]=bi2[2]; bv2[2]=v; bi2[2]=pp; }
                    else { bv2[3]=v; bi2[3]=pp; }
                }
            }
        ((int4*)idxout)[pix] = make_int4(bi2[0], bi2[1], bi2[2], bi2[3]);
    }
}

// ---------------- expand nn_w into zero-padded GEMM B-matrix Wmat[k][n] ----------------
// k = j*576 + uv*64 + c   (j in 4, uv=(u,v) in 9, c in 64)
// n = o*9 + t             (o in 64, t=(ty,tx) in 9)
__global__ __launch_bounds__(256) void wmat_kernel(const float* __restrict__ nn_w,
                                                   float* __restrict__ Wmat)
{
    int gid = blockIdx.x * 256 + threadIdx.x;   // 2304*576 total
    int k = gid / 576, n = gid % 576;
    int j = k / 576 == 0 ? k / 576 : k / 576;   // placeholder to keep compiler calm
    j = k / 576;
    int r = k % 576;
    int uv = r >> 6, c = r & 63;
    int u = uv / 3, v = uv % 3;
    int o = n / 9, t = n % 9;
    int ty = t / 3, tx = t % 3;
    int ky = u - ty + 1, kx = v - tx + 1;
    float val = 0.f;
    if ((unsigned)ky < 3u && (unsigned)kx < 3u)
        val = nn_w[(((size_t)o * 256 + j * 64 + c) * 3 + ky) * 3 + kx];
    Wmat[gid] = val;
}

// ---------------- stage-4 GEMM: Cbuf[m=pixel][n=(o,t)] = sum_k patch[m][k] * Wmat[k][n] ----
#define BM 128
#define BN 64
#define BK 16
__global__ __launch_bounds__(256) void gemm_kernel(const float* __restrict__ nbrT,
                                                   const int* __restrict__ idxb,
                                                   const float* __restrict__ Wmat,
                                                   float* __restrict__ Cbuf)
{
    const int n0 = blockIdx.x * BN;   // gridDim.x = 9
    const int m0 = blockIdx.y * BM;   // gridDim.y = 256
    const int tid = threadIdx.x;
    const int tx = tid & 15, ty = tid >> 4;

    __shared__ float sA[BK][BM];
    __shared__ float sB[BK][BN];

    float acc[8][4] = {};

    const int am = tid & 127;
    const int ag = tid >> 7;          // 0 or 1 -> covers kk = ag*8 .. ag*8+7
    const int pm = m0 + am;
    const int bpix = pm >> 14, hwm = pm & (HWSZ - 1), hm = hwm >> 7, wm = hwm & 127;

    const int bkk = tid >> 4;         // B-tile loader coords
    const int bn4 = (tid & 15) << 2;

    for (int k0 = 0; k0 < 2304; k0 += BK) {
        const int j = k0 / 576;
        const int r = k0 % 576;
        const int uv = r >> 6;
        const int c0 = r & 63;
        const int u = uv / 3, v = uv % 3;

        const int pidx = idxb[pm * 4 + j];
        const int ph = pidx / 11, pw = pidx % 11;
        const int y = hm + ph + u - 6;
        const int x = wm + pw + v - 6;
        float4 v0 = {0, 0, 0, 0}, v1 = {0, 0, 0, 0};
        if ((unsigned)y < HH && (unsigned)x < WW) {
            const float4* src = (const float4*)(nbrT +
                ((((size_t)bpix << 14) | (y << 7) | x)) * 64 + c0 + ag * 8);
            v0 = src[0]; v1 = src[1];
        }
        float4 bload = *(const float4*)(Wmat + (size_t)(k0 + bkk) * 576 + n0 + bn4);

        __syncthreads();   // previous iter's LDS reads done
        {
            const int kk0 = ag * 8;
            sA[kk0 + 0][am] = v0.x; sA[kk0 + 1][am] = v0.y;
            sA[kk0 + 2][am] = v0.z; sA[kk0 + 3][am] = v0.w;
            sA[kk0 + 4][am] = v1.x; sA[kk0 + 5][am] = v1.y;
            sA[kk0 + 6][am] = v1.z; sA[kk0 + 7][am] = v1.w;
            *(float4*)&sB[bkk][bn4] = bload;
        }
        __syncthreads();

#pragma unroll
        for (int kk = 0; kk < BK; ++kk) {
            float4 a0 = *(float4*)&sA[kk][ty * 8];
            float4 a1 = *(float4*)&sA[kk][ty * 8 + 4];
            float4 bv = *(float4*)&sB[kk][tx * 4];
            float av[8] = {a0.x, a0.y, a0.z, a0.w, a1.x, a1.y, a1.z, a1.w};
            float bw[4] = {bv.x, bv.y, bv.z, bv.w};
#pragma unroll
            for (int i = 0; i < 8; ++i)
#pragma unroll
                for (int jj = 0; jj < 4; ++jj)
                    acc[i][jj] = fmaf(av[i], bw[jj], acc[i][jj]);
        }
    }
#pragma unroll
    for (int i = 0; i < 8; ++i) {
        float4 o4 = {acc[i][0], acc[i][1], acc[i][2], acc[i][3]};
        *(float4*)(Cbuf + (size_t)(m0 + ty * 8 + i) * 576 + n0 + tx * 4) = o4;
    }
}

// ---------------- mask combine + bias + LeakyReLU -> agg (B,64,H,W) ----------------
__global__ __launch_bounds__(256) void combine_kernel(const float* __restrict__ Cbuf,
                                                      const float* __restrict__ maskraw,
                                                      const float* __restrict__ nn_b,
                                                      float* __restrict__ agg)
{
    int gid = blockIdx.x * 256 + threadIdx.x;   // B*64*HW total
    int hw = gid & (HWSZ - 1);
    int z = gid >> 14;                          // 0..127
    int b = z >> 6, o = z & 63;
    int g = o >> 3;
    size_t pix = ((size_t)b << 14) + hw;
    const float* cp = Cbuf + pix * 576 + o * 9;
    float bo = nn_b[o];
    float s = 0.f;
#pragma unroll
    for (int t = 0; t < 9; ++t) {
        float m = maskraw[(((size_t)b * 72 + g * 9 + t) << 14) + hw];
        s += (cp[t] + bo) * m;
    }
    s = (s >= 0.f) ? s : 0.1f * s;
    agg[((size_t)(b * 64 + o) << 14) + hw] = s;
}

extern "C" void kernel_launch(void* const* d_in, const int* in_sizes, int n_in,
                              void* d_out, int out_size, void* d_ws, size_t ws_size,
                              hipStream_t stream)
{
    const float* nbr = (const float*)d_in[0];
    const float* ref = (const float*)d_in[1];
    const float* c1w = (const float*)d_in[2];
    const float* c1b = (const float*)d_in[3];
    const float* c2w = (const float*)d_in[4];
    const float* c2b = (const float*)d_in[5];
    const float* mw  = (const float*)d_in[6];
    const float* mb  = (const float*)d_in[7];
    const float* nnw = (const float*)d_in[8];
    const float* nnb = (const float*)d_in[9];
    const float* aw  = (const float*)d_in[10];
    const float* ab  = (const float*)d_in[11];
    float* out = (float*)d_out;

    float* ws = (float*)d_ws;
    // offsets in floats; total = 31,080,448 floats = ~118.6 MiB
    float* wf1     = ws + 0;              // 2,097,152  (reused as nbrT after conv2)
    float* wf2     = ws + 2097152;        // 2,097,152  (reused as f1t after mask conv)
    float* maskraw = ws + 4194304;        // 2,359,296
    float* f2t     = ws + 6553600;        // 2,097,152
    float* Dbuf    = ws + 8650752;        // 3,964,928 (D) / 18,874,368 (Cbuf, after topk)
    int*   idxb    = (int*)(ws + 27525120); // 131,072 ints
    float* Wmat    = ws + 27656192;       // 1,327,104
    float* agg     = ws + 28983296;       // 2,097,152
    float* nbrT    = wf1;                 // alias (wf1 dead after conv2)
    float* f1t     = wf2;                 // alias (wf2 dead after mask conv)
    float* Cbuf    = Dbuf;                // alias (D dead after topk)

    dim3 blk(256);

    // mask branch
    conv3x3_kernel<<<dim3(8, 8, 16), blk, 0, stream>>>(nbr, ref, 64, 128, c1w, c1b, wf1, 64);
    conv3x3_kernel<<<dim3(8, 8, 16), blk, 0, stream>>>(wf1, wf1, 64, 64, c2w, c2b, wf2, 64);
    conv3x3_kernel<<<dim3(8, 8, 18), blk, 0, stream>>>(wf2, wf2, 64, 64, mw, mb, maskraw, 72);

    // l2norm + transpose (and raw transpose of nbr for gathers)
    l2t_kernel<<<512, blk, 0, stream>>>(ref, f1t, 1);
    l2t_kernel<<<512, blk, 0, stream>>>(nbr, f2t, 1);
    l2t_kernel<<<512, blk, 0, stream>>>(nbr, nbrT, 0);

    // correlation dots + box-sum/top-4
    dot_kernel<<<dim3(128, 4), blk, 0, stream>>>(f1t, f2t, Dbuf);
    topk_kernel<<<512, blk, 0, stream>>>(Dbuf, idxb);

    // stage-4: weight expansion, gathered GEMM, mask combine
    wmat_kernel<<<5184, blk, 0, stream>>>(nnw, Wmat);
    gemm_kernel<<<dim3(9, 256), blk, 0, stream>>>(nbrT, idxb, Wmat, Cbuf);
    combine_kernel<<<8192, blk, 0, stream>>>(Cbuf, maskraw, nnb, agg);

    // final conv on concat(agg, ref)
    conv3x3_kernel<<<dim3(8, 8, 16), blk, 0, stream>>>(agg, ref, 64, 128, aw, ab, out, 64);
}

// Round 2
// 432.648 us; speedup vs baseline: 5.2299x; 5.2299x over previous
//
#include <hip/hip_runtime.h>
#include <hip/hip_bf16.h>
#include <math.h>

#define HH 128
#define WW 128
#define HWSZ 16384

typedef __attribute__((ext_vector_type(8))) short short8;
typedef __attribute__((ext_vector_type(4))) float f32x4;

__device__ inline ushort f2bf(float f) {
    __hip_bfloat16 h = __float2bfloat16(f);
    return *reinterpret_cast<ushort*>(&h);
}

// ---------------- l2norm+transpose: writes fp32 normed [pix][64] and raw bf16 into cat buffers ----
__global__ __launch_bounds__(256) void l2t2_kernel(const float* __restrict__ in,
                                                   float* __restrict__ normT,
                                                   ushort* __restrict__ d1,
                                                   ushort* __restrict__ d2)
{
    const int pix0 = blockIdx.x * 64;
    const int b = pix0 >> 14;
    const int hw0 = pix0 & (HWSZ - 1);
    __shared__ float s[64][65];
    __shared__ float sinv[64];
    const int tid = threadIdx.x;
    {
        const int p = tid & 63, c4 = tid >> 6;
#pragma unroll
        for (int r = 0; r < 16; ++r) {
            int c = r * 4 + c4;
            s[c][p] = in[(((size_t)b * 64 + c) << 14) + hw0 + p];
        }
    }
    __syncthreads();
    if (tid < 64) {
        float sum = 0.f;
#pragma unroll
        for (int c = 0; c < 64; ++c) { float v = s[c][tid]; sum = fmaf(v, v, sum); }
        sinv[tid] = 1.f / fmaxf(sqrtf(sum), 1e-12f);
    }
    __syncthreads();
    {
        const int c = tid & 63, p4 = tid >> 6;
#pragma unroll
        for (int r = 0; r < 16; ++r) {
            int pp = r * 4 + p4;
            float v = s[c][pp];
            normT[(size_t)(pix0 + pp) * 64 + c] = v * sinv[pp];
            ushort bv = f2bf(v);
            d1[(size_t)(pix0 + pp) * 128 + c] = bv;
            if (d2) d2[(size_t)(pix0 + pp) * 128 + c] = bv;
        }
    }
}

// ---------------- per-displacement dot products D[b][p][hw] (fp32 — feeds top-k) ----------------
__global__ __launch_bounds__(256) void dot_kernel(const float* __restrict__ f1t,
                                                  const float* __restrict__ f2t,
                                                  float* __restrict__ D)
{
    const int pix = blockIdx.x * 256 + threadIdx.x;
    const int q = blockIdx.y;
    const int b = pix >> 14, hw = pix & (HWSZ - 1), h = hw >> 7, w = hw & 127;
    float4 f1[16];
    const float4* f1p = (const float4*)(f1t + (size_t)pix * 64);
#pragma unroll
    for (int i = 0; i < 16; ++i) f1[i] = f1p[i];
    const size_t dbase = ((size_t)b * 121) << 14;
    for (int p = q; p < 121; p += 4) {
        int dy = p / 11 - 5, dx = p % 11 - 5;
        int y = h + dy, x = w + dx;
        float s = 0.f;
        if ((unsigned)y < HH && (unsigned)x < WW) {
            const float4* f2p = (const float4*)(f2t + ((((size_t)b << 14) | (y << 7) | x)) * 64);
#pragma unroll
            for (int i = 0; i < 16; ++i) {
                float4 a = f1[i], c = f2p[i];
                s += a.x * c.x + a.y * c.y + a.z * c.z + a.w * c.w;
            }
        }
        D[dbase + ((size_t)p << 14) + hw] = s;
    }
}

// ---------------- 3x3 box-sum of D + stable top-4; outputs packed (ph | pw<<16) ----------------
__global__ __launch_bounds__(256) void topk_kernel(const float* __restrict__ D,
                                                   int* __restrict__ idxout)
{
    const int tid = threadIdx.x;
    const int lp = tid & 63, tq = tid >> 6;
    const int pix = blockIdx.x * 64 + lp;
    const int b = pix >> 14, hw = pix & (HWSZ - 1), h = hw >> 7, w = hw & 127;
    const size_t dbase = ((size_t)b * 121) << 14;

    float bv[4] = {-1e30f, -1e30f, -1e30f, -1e30f};
    int   bi[4] = {1000, 1000, 1000, 1000};
    for (int p = tq; p < 121; p += 4) {
        float s = 0.f;
#pragma unroll
        for (int dy = -1; dy <= 1; ++dy) {
            int y = h + dy; if ((unsigned)y >= HH) continue;
#pragma unroll
            for (int dx = -1; dx <= 1; ++dx) {
                int x = w + dx; if ((unsigned)x >= WW) continue;
                s += D[dbase + ((size_t)p << 14) + (y << 7) + x];
            }
        }
        if (s > bv[3]) {
            if (s > bv[0]) { bv[3]=bv[2];bi[3]=bi[2]; bv[2]=bv[1];bi[2]=bi[1]; bv[1]=bv[0];bi[1]=bi[0]; bv[0]=s; bi[0]=p; }
            else if (s > bv[1]) { bv[3]=bv[2];bi[3]=bi[2]; bv[2]=bv[1];bi[2]=bi[1]; bv[1]=s; bi[1]=p; }
            else if (s > bv[2]) { bv[3]=bv[2];bi[3]=bi[2]; bv[2]=s; bi[2]=p; }
            else { bv[3]=s; bi[3]=p; }
        }
    }
    __shared__ float sv[4][64][4];
    __shared__ int   si[4][64][4];
#pragma unroll
    for (int r = 0; r < 4; ++r) { sv[tq][lp][r] = bv[r]; si[tq][lp][r] = bi[r]; }
    __syncthreads();
    if (tq == 0) {
        float bv2[4] = {-1e30f, -1e30f, -1e30f, -1e30f};
        int   bi2[4] = {100000, 100000, 100000, 100000};
#pragma unroll
        for (int t = 0; t < 4; ++t)
#pragma unroll
            for (int r = 0; r < 4; ++r) {
                float v = sv[t][lp][r]; int pp = si[t][lp][r];
                bool g3 = (v > bv2[3]) || (v == bv2[3] && pp < bi2[3]);
                if (g3) {
                    bool g0 = (v > bv2[0]) || (v == bv2[0] && pp < bi2[0]);
                    bool g1 = (v > bv2[1]) || (v == bv2[1] && pp < bi2[1]);
                    bool g2 = (v > bv2[2]) || (v == bv2[2] && pp < bi2[2]);
                    if (g0) { bv2[3]=bv2[2];bi2[3]=bi2[2]; bv2[2]=bv2[1];bi2[2]=bi2[1]; bv2[1]=bv2[0];bi2[1]=bi2[0]; bv2[0]=v; bi2[0]=pp; }
                    else if (g1) { bv2[3]=bv2[2];bi2[3]=bi2[2]; bv2[2]=bv2[1];bi2[2]=bi2[1]; bv2[1]=v; bi2[1]=pp; }
                    else if (g2) { bv2[3]=bv2[2];bi2[3]=bi2[2]; bv2[2]=v; bi2[2]=pp; }
                    else { bv2[3]=v; bi2[3]=pp; }
                }
            }
        int p0 = (bi2[0] / 11) | ((bi2[0] % 11) << 16);
        int p1 = (bi2[1] / 11) | ((bi2[1] % 11) << 16);
        int p2 = (bi2[2] / 11) | ((bi2[2] % 11) << 16);
        int p3 = (bi2[3] / 11) | ((bi2[3] % 11) << 16);
        ((int4*)idxout)[pix] = make_int4(p0, p1, p2, p3);
    }
}

// ---------------- conv-weight transform: WT[o][tap*Cin + c] bf16, zero-padded rows to Npad ----
__global__ __launch_bounds__(256) void wtconv_kernel(const float* __restrict__ w,
                                                     ushort* __restrict__ WT,
                                                     int Cin, int Cout)
{
    int gid = blockIdx.x * 256 + threadIdx.x;
    int kc = 9 * Cin;
    int o = gid / kc, rem = gid % kc;
    int tap = rem / Cin, c = rem % Cin;
    float val = (o < Cout) ? w[((size_t)o * Cin + c) * 9 + tap] : 0.f;
    WT[gid] = f2bf(val);
}

// ---------------- stage-4 weight: WmatT[n=o*9+t][k=j*576+uv*64+c] bf16 (zero-padded taps) ----
__global__ __launch_bounds__(256) void wmatT_kernel(const float* __restrict__ nnw,
                                                    ushort* __restrict__ WmatT)
{
    int gid = blockIdx.x * 256 + threadIdx.x;   // 576*2304
    int n = gid / 2304, k = gid % 2304;
    int o = n / 9, t = n % 9;
    int ty = t / 3, tx = t % 3;
    int j = k / 576, r = k % 576;
    int uv = r >> 6, c = r & 63;
    int u = uv / 3, v = uv % 3;
    int ky = u - ty + 1, kx = v - tx + 1;
    float val = 0.f;
    if ((unsigned)ky < 3u && (unsigned)kx < 3u)
        val = nnw[((size_t)o * 256 + j * 64 + c) * 9 + ky * 3 + kx];
    WmatT[gid] = f2bf(val);
}

// ---------------- unified MFMA GEMM: conv-gather (MODE 0) or patch-gather (MODE 1) ----------------
// BM=BN=BK=64, 256 threads = 4 waves (2x2), XOR-swizzled LDS (T2), bf16 16x16x32 MFMA.
template<int MODE, int CINPT, int OUTFMT>
__global__ __launch_bounds__(256) void mmconv_kernel(
    const ushort* __restrict__ srcT, int sstride,
    const int* __restrict__ idxp,
    const ushort* __restrict__ WT, int Ktot,
    const float* __restrict__ bias,
    void* __restrict__ outp, int ostride, int nvalid)
{
    const int n0 = blockIdx.x * 64;
    const int m0 = blockIdx.y * 64;
    const int tid = threadIdx.x;
    const int r = tid >> 2, q = tid & 3;       // staging: 4 threads per row, 32B each

    __shared__ __align__(16) char sA[64 * 128];
    __shared__ __align__(16) char sB[64 * 128];

    const int pm = m0 + r;
    const int b = pm >> 14, hw = pm & (HWSZ - 1), h = hw >> 7, w = hw & 127;
    const size_t browoff = (size_t)(n0 + r) * Ktot + q * 16;

    const int lane = tid & 63, wid = tid >> 6;
    const int wr = wid >> 1, wc = wid & 1;
    const int lr = lane >> 4, lc = lane & 15;

    f32x4 acc[2][2] = {};

    for (int k0 = 0; k0 < Ktot; k0 += 64) {
        int y, x, c0;
        if (MODE == 0) {
            int tap = k0 / CINPT; c0 = k0 % CINPT;
            y = h + tap / 3 - 1; x = w + tap % 3 - 1;
        } else {
            int j = k0 / 576; int uv = (k0 % 576) >> 6; c0 = 0;
            int pk = idxp[pm * 4 + j];
            y = h + (pk & 0xffff) + uv / 3 - 6;
            x = w + (pk >> 16) + uv % 3 - 6;
        }
        uint4 a0 = {0,0,0,0}, a1 = {0,0,0,0};
        if ((unsigned)y < (unsigned)HH && (unsigned)x < (unsigned)WW) {
            const uint4* p = (const uint4*)(srcT +
                (size_t)((b << 14) | (y << 7) | x) * sstride + c0 + q * 16);
            a0 = p[0]; a1 = p[1];
        }
        const uint4* bp = (const uint4*)(WT + browoff + k0);
        uint4 b0 = bp[0], b1 = bp[1];

        __syncthreads();
        {
            const int u0 = q * 2;
            *(uint4*)(sA + r * 128 + ((u0    ) ^ (r & 7)) * 16) = a0;
            *(uint4*)(sA + r * 128 + ((u0 + 1) ^ (r & 7)) * 16) = a1;
            *(uint4*)(sB + r * 128 + ((u0    ) ^ (r & 7)) * 16) = b0;
            *(uint4*)(sB + r * 128 + ((u0 + 1) ^ (r & 7)) * 16) = b1;
        }
        __syncthreads();

#pragma unroll
        for (int ks = 0; ks < 2; ++ks) {
            short8 af[2], bfr[2];
            const int u = lr + ks * 4;
#pragma unroll
            for (int f = 0; f < 2; ++f) {
                int rr = wr * 32 + f * 16 + lc;
                af[f] = *(const short8*)(sA + rr * 128 + (u ^ (rr & 7)) * 16);
            }
#pragma unroll
            for (int g = 0; g < 2; ++g) {
                int nn = wc * 32 + g * 16 + lc;
                bfr[g] = *(const short8*)(sB + nn * 128 + (u ^ (nn & 7)) * 16);
            }
#pragma unroll
            for (int f = 0; f < 2; ++f)
#pragma unroll
                for (int g = 0; g < 2; ++g)
                    acc[f][g] = __builtin_amdgcn_mfma_f32_16x16x32_bf16(af[f], bfr[g], acc[f][g], 0, 0, 0);
        }
    }

#pragma unroll
    for (int f = 0; f < 2; ++f)
#pragma unroll
        for (int g = 0; g < 2; ++g) {
            const int col = n0 + wc * 32 + g * 16 + lc;
            float bv = 0.f;
            if (MODE == 0) bv = (col < nvalid) ? bias[col] : 0.f;
#pragma unroll
            for (int reg = 0; reg < 4; ++reg) {
                const int m = m0 + wr * 32 + f * 16 + lr * 4 + reg;
                float v = acc[f][g][reg] + bv;
                if (OUTFMT == 0) {
                    ((ushort*)outp)[(size_t)m * ostride + col] = f2bf(v);
                } else if (OUTFMT == 1) {
                    if (col < nvalid)
                        ((float*)outp)[(size_t)m * ostride + col] = v;
                } else {
                    int bb = m >> 14, hww = m & (HWSZ - 1);
                    ((float*)outp)[((size_t)(bb * 64 + col) << 14) + hww] = v;
                }
            }
        }
}

// ---------------- mask combine + bias + LeakyReLU -> agg bf16 into cat2T[:,0:64] ----------------
__global__ __launch_bounds__(256) void combine_kernel(const float* __restrict__ Cbuf,
                                                      const float* __restrict__ maskcl,
                                                      const float* __restrict__ nn_b,
                                                      ushort* __restrict__ aggout)
{
    int gid = blockIdx.x * 256 + threadIdx.x;   // 32768*64
    int o = gid & 63;
    size_t pix = (size_t)(gid >> 6);
    int g = o >> 3;
    const float* cp = Cbuf + pix * 576 + o * 9;
    const float* mp = maskcl + pix * 72 + g * 9;
    float bo = nn_b[o];
    float s = 0.f;
#pragma unroll
    for (int t = 0; t < 9; ++t) s += (cp[t] + bo) * mp[t];
    s = (s >= 0.f) ? s : 0.1f * s;
    aggout[pix * 128 + o] = f2bf(s);
}

extern "C" void kernel_launch(void* const* d_in, const int* in_sizes, int n_in,
                              void* d_out, int out_size, void* d_ws, size_t ws_size,
                              hipStream_t stream)
{
    const float* nbr = (const float*)d_in[0];
    const float* ref = (const float*)d_in[1];
    const float* c1w = (const float*)d_in[2];
    const float* c1b = (const float*)d_in[3];
    const float* c2w = (const float*)d_in[4];
    const float* c2b = (const float*)d_in[5];
    const float* mw  = (const float*)d_in[6];
    const float* mb  = (const float*)d_in[7];
    const float* nnw = (const float*)d_in[8];
    const float* nnb = (const float*)d_in[9];
    const float* aw  = (const float*)d_in[10];
    const float* ab  = (const float*)d_in[11];
    float* out = (float*)d_out;

    char* W = (char*)d_ws;
    ushort* catT   = (ushort*)(W + 0);          // 8,388,608 B  [pix][128]: nbr@0, ref@64
    ushort* cat2T  = (ushort*)(W + 8388608);    // 8,388,608 B  [pix][128]: agg@0, ref@64
    ushort* wf1    = (ushort*)(W + 16777216);   // 4,194,304 B  [pix][64]
    ushort* wf2    = (ushort*)(W + 20971520);   // 4,194,304 B
    float*  maskcl = (float*)(W + 25165824);    // 9,437,184 B  [pix][72]
    int*    idxp   = (int*)(W + 34603008);      //   524,288 B  [pix][4] packed ph|pw<<16
    ushort* WT1    = (ushort*)(W + 35127296);   //   147,456 B  [64][1152]
    ushort* WT2    = (ushort*)(W + 35274752);   //    73,728 B  [64][576]
    ushort* WTm    = (ushort*)(W + 35348480);   //   147,456 B  [128][576] (rows>=72 zero)
    ushort* WTa    = (ushort*)(W + 35495936);   //   147,456 B  [64][1152]
    ushort* WmatT  = (ushort*)(W + 35643392);   // 2,654,208 B  [576][2304]
    float*  f1t    = (float*)(W + 38297600);    // 8,388,608 B  (dead after dot)
    float*  f2t    = (float*)(W + 46686208);    // 8,388,608 B  (dead after dot)
    float*  Dbuf   = (float*)(W + 55074816);    // 15,859,712 B (dead after topk)
    float*  Cbuf   = (float*)(W + 38297600);    // 75,497,472 B (overlays f1t/f2t/D) -> ends ~108.5MB

    dim3 blk(256);

    // transposes + l2norm (f1t/f2t fp32 for fp32 top-k path; raw bf16 into cat buffers)
    l2t2_kernel<<<512, blk, 0, stream>>>(ref, f1t, catT + 64, cat2T + 64);
    l2t2_kernel<<<512, blk, 0, stream>>>(nbr, f2t, catT + 0, (ushort*)nullptr);

    // weight transforms (tiny)
    wtconv_kernel<<<288, blk, 0, stream>>>(c1w, WT1, 128, 64);
    wtconv_kernel<<<144, blk, 0, stream>>>(c2w, WT2, 64, 64);
    wtconv_kernel<<<288, blk, 0, stream>>>(mw,  WTm, 64, 72);
    wtconv_kernel<<<288, blk, 0, stream>>>(aw,  WTa, 128, 64);
    wmatT_kernel<<<5184, blk, 0, stream>>>(nnw, WmatT);

    // mask branch (MFMA implicit-GEMM convs)
    mmconv_kernel<0, 128, 0><<<dim3(1, 512), blk, 0, stream>>>(catT, 128, nullptr, WT1, 1152, c1b, wf1, 64, 64);
    mmconv_kernel<0, 64, 0><<<dim3(1, 512), blk, 0, stream>>>(wf1, 64, nullptr, WT2, 576, c2b, wf2, 64, 64);
    mmconv_kernel<0, 64, 1><<<dim3(2, 512), blk, 0, stream>>>(wf2, 64, nullptr, WTm, 576, mb, maskcl, 72, 72);

    // correlation (fp32) + stable top-4
    dot_kernel<<<dim3(128, 4), blk, 0, stream>>>(f1t, f2t, Dbuf);
    topk_kernel<<<512, blk, 0, stream>>>(Dbuf, idxp);

    // stage-4 gathered GEMM (bf16 MFMA): Cbuf[pix][576]
    mmconv_kernel<1, 64, 1><<<dim3(9, 512), blk, 0, stream>>>(catT, 128, idxp, WmatT, 2304, nullptr, Cbuf, 576, 576);

    // mask-weighted combine + LeakyReLU -> agg half of cat2T
    combine_kernel<<<8192, blk, 0, stream>>>(Cbuf, maskcl, nnb, cat2T);

    // final conv on concat(agg, ref) -> NCHW fp32 d_out
    mmconv_kernel<0, 128, 2><<<dim3(1, 512), blk, 0, stream>>>(cat2T, 128, nullptr, WTa, 1152, ab, out, 0, 64);
}